// Round 3
// baseline (291.841 us; speedup 1.0000x reference)
//
#include <hip/hip_runtime.h>

typedef _Float16 f16;
typedef f16 f16x4 __attribute__((ext_vector_type(4)));
typedef f16 f16x8 __attribute__((ext_vector_type(8)));
typedef __fp16 h16x2 __attribute__((ext_vector_type(2)));
typedef float floatx4 __attribute__((ext_vector_type(4)));

#define LDT 72  // transpose-kernel tile stride (f16), 2-way reads are free
#define LDE 136 // gemm1 epilogue V-transpose tile stride (16B-aligned rows for uint4)
#define QSCALE 11.5415603271117f  // 8 * log2(e): score computed in log2 domain

// direct global->LDS DMA, 16B per lane. LDS dest is WAVE-UNIFORM base;
// HW scatters lane i at base + i*16B. Global src is per-lane.
__device__ __forceinline__ void gld16(const void* g, void* l) {
  __builtin_amdgcn_global_load_lds((const __attribute__((address_space(1))) unsigned int*)g,
                                   (__attribute__((address_space(3))) unsigned int*)l,
                                   16, 0, 0);
}

// x [8192,768] fp32 -> f16, vectorized 32B-in / 16B-out per thread (memory-bound)
__global__ __launch_bounds__(256) void cvt_f32_f16(const float* __restrict__ in,
                                                   f16* __restrict__ out) {
  size_t i = ((size_t)blockIdx.x * 256 + threadIdx.x) * 8;
  float4 v0 = *(const float4*)(in + i);
  float4 v1 = *(const float4*)(in + i + 4);
  f16x8 h = {(f16)v0.x, (f16)v0.y, (f16)v0.z, (f16)v0.w,
             (f16)v1.x, (f16)v1.y, (f16)v1.z, (f16)v1.w};
  *(f16x8*)(out + i) = h;
}

// W [K][N] fp32 -> Wt [N][K] fp16, 64x64 tiles via LDS: coalesced both sides
__global__ __launch_bounds__(256) void transpose_f32_f16_tiled(const float* __restrict__ in,
                                                               f16* __restrict__ out,
                                                               int K, int N) {
  __shared__ f16 tile[64][LDT];
  int k0 = blockIdx.x * 64, n0 = blockIdx.y * 64;
  int tid = threadIdx.x;
  int r = tid >> 4, c4 = (tid & 15) * 4;
  for (int p = 0; p < 4; ++p) {
    int rr = r + p * 16;
    float4 v = *(const float4*)(in + (size_t)(k0 + rr) * N + n0 + c4);
    tile[c4 + 0][rr] = (f16)v.x;
    tile[c4 + 1][rr] = (f16)v.y;
    tile[c4 + 2][rr] = (f16)v.z;
    tile[c4 + 3][rr] = (f16)v.w;
  }
  __syncthreads();
  int rn = tid >> 3, ck = (tid & 7) * 8;
  for (int p = 0; p < 2; ++p) {
    int rr = rn + p * 32;
    *(uint4*)(out + (size_t)(n0 + rr) * K + k0 + ck) = *(const uint4*)(&tile[rr][ck]);
  }
}

// qkv = x16 @ WqkvT^T (both f16, fp32 acc), global_load_lds staging.
__global__ __launch_bounds__(256) void gemm1_qkv(const f16* __restrict__ A,
                                                 const f16* __restrict__ Bt,
                                                 f16* __restrict__ q16, f16* __restrict__ k16,
                                                 f16* __restrict__ vt) {
  __shared__ f16 smem[17408];
  f16* As = smem;
  f16* Bs = smem + 8192;
  int tid = threadIdx.x;
  int lane = tid & 63, wid = tid >> 6;
  int quad = lane >> 4, l16 = lane & 15;
  int wy = wid >> 1, wx = wid & 1;
  int m0 = blockIdx.x * 128, n0 = blockIdx.y * 128;
  int gr = lane >> 3, gc = (lane & 7) * 8;
  floatx4 acc[4][4] = {};
  for (int k0 = 0; k0 < 768; k0 += 64) {
    for (int p = 0; p < 4; ++p) {
      int c = wid * 4 + p;
      int row = c * 8 + gr;
      gld16(A + (size_t)(m0 + row) * 768 + k0 + gc, As + c * 512);
      gld16(Bt + (size_t)(n0 + row) * 768 + k0 + gc, Bs + c * 512);
    }
    __syncthreads();
    for (int kk = 0; kk < 64; kk += 32) {
      f16x8 af[4], bfr[4];
      for (int i = 0; i < 4; ++i)
        af[i] = *(const f16x8*)(As + (wy * 64 + i * 16 + l16) * 64 + kk + quad * 8);
      for (int j = 0; j < 4; ++j)
        bfr[j] = *(const f16x8*)(Bs + (wx * 64 + j * 16 + l16) * 64 + kk + quad * 8);
      for (int i = 0; i < 4; ++i)
        for (int j = 0; j < 4; ++j)
          acc[i][j] = __builtin_amdgcn_mfma_f32_16x16x32_f16(af[i], bfr[j], acc[i][j], 0, 0, 0);
    }
    __syncthreads();
  }
  int b = m0 >> 11, t0 = m0 & 2047;
  if (n0 < 1536) {
    for (int i = 0; i < 4; ++i)
      for (int j = 0; j < 4; ++j)
        for (int r = 0; r < 4; ++r) {
          int t = t0 + wy * 64 + i * 16 + quad * 4 + r;
          int col = n0 + wx * 64 + j * 16 + l16;
          float a = acc[i][j][r];
          if (col < 768) {
            int h = col >> 6, d = col & 63;
            q16[((size_t)(b * 12 + h)) * 131072 + (size_t)t * 64 + d] = (f16)(a * QSCALE);
          } else {
            int c = col - 768;
            int h = c >> 6, d = c & 63;
            k16[((size_t)(b * 12 + h)) * 131072 + (size_t)t * 64 + d] = (f16)a;
          }
        }
  } else {
    f16* Vtile = smem;  // 128*LDE = 34816 B
    int h0 = (n0 - 1536) >> 6;
    for (int i = 0; i < 4; ++i)
      for (int j = 0; j < 4; ++j) {
        int cl = wx * 64 + j * 16 + l16;
        int rl = wy * 64 + i * 16 + quad * 4;
        for (int r = 0; r < 4; ++r)
          Vtile[cl * LDE + rl + r] = (f16)acc[i][j][r];
      }
    __syncthreads();
    int u = tid & 15;
    for (int p = 0; p < 8; ++p) {
      int c = (tid >> 4) + p * 16;
      *(uint4*)(vt + ((size_t)(b * 12 + h0 + (c >> 6))) * 131072 +
                (size_t)(c & 63) * 2048 + t0 + u * 8) =
          *(const uint4*)(Vtile + c * LDE + u * 8);
    }
  }
}

// C[M,N](fp32) = A[M,K](f16) * Bt[N,K]^T(f16), global_load_lds staging
__global__ __launch_bounds__(256) void gemm_bt_f16(const f16* __restrict__ A,
                                                   const f16* __restrict__ Bt,
                                                   float* __restrict__ C,
                                                   int M, int N, int K) {
  __shared__ f16 As[8192];
  __shared__ f16 Bs[8192];
  int tid = threadIdx.x;
  int lane = tid & 63, wid = tid >> 6;
  int quad = lane >> 4, l16 = lane & 15;
  int wy = wid >> 1, wx = wid & 1;
  int m0 = blockIdx.x * 128, n0 = blockIdx.y * 128;
  int gr = lane >> 3, gc = (lane & 7) * 8;
  floatx4 acc[4][4] = {};
  for (int k0 = 0; k0 < K; k0 += 64) {
    for (int p = 0; p < 4; ++p) {
      int c = wid * 4 + p;
      int row = c * 8 + gr;
      gld16(A + (size_t)(m0 + row) * K + k0 + gc, As + c * 512);
      gld16(Bt + (size_t)(n0 + row) * K + k0 + gc, Bs + c * 512);
    }
    __syncthreads();
    for (int kk = 0; kk < 64; kk += 32) {
      f16x8 af[4], bfr[4];
      for (int i = 0; i < 4; ++i)
        af[i] = *(const f16x8*)(As + (wy * 64 + i * 16 + l16) * 64 + kk + quad * 8);
      for (int j = 0; j < 4; ++j)
        bfr[j] = *(const f16x8*)(Bs + (wx * 64 + j * 16 + l16) * 64 + kk + quad * 8);
      for (int i = 0; i < 4; ++i)
        for (int j = 0; j < 4; ++j)
          acc[i][j] = __builtin_amdgcn_mfma_f32_16x16x32_f16(af[i], bfr[j], acc[i][j], 0, 0, 0);
    }
    __syncthreads();
  }
  for (int i = 0; i < 4; ++i) {
    int row = m0 + wy * 64 + i * 16 + quad * 4;
    for (int j = 0; j < 4; ++j) {
      int col = n0 + wx * 64 + j * 16 + l16;
      for (int r = 0; r < 4; ++r)
        C[(size_t)(row + r) * N + col] = acc[i][j][r];
    }
  }
}

// Flash attention v10: v9 structure (4 waves x 32 q-rows, dbuf gld_lds) with the
// VALU diet: precomputed swizzled LDS base pointers (all kt-loop ds_reads become
// base+imm, zero per-read VALU), const-zero MFMA accumulator inits, balanced
// max tree, split rowsum chains, defer-max (THR=8, log2 domain), setprio(1)
// around MFMA clusters.
__global__ __launch_bounds__(256, 1) void flash_attn(const f16* __restrict__ q16,
                                                     const f16* __restrict__ k16,
                                                     const f16* __restrict__ vT,
                                                     f16* __restrict__ y) {
  // f16-unit layout: KsA@0 KsB@8192 VtA@16384 VtB@24576 (64 KB total).
  // Byte offsets of all imm-offset reads stay < 65536.
  __shared__ f16 lds[32768];
  const int T = 2048;
  int xcd = blockIdx.x & 7, yb = blockIdx.x >> 3;  // yb in [0,96)
  int bh = xcd * 6 + (yb >> 4);
  int qt = yb & 15;
  int b = bh / 12, h = bh - b * 12;
  int tid = threadIdx.x;
  int lane = tid & 63, wid = tid >> 6;             // wid in [0,4)
  int quad = lane >> 4, l16 = lane & 15;
  size_t hb = (size_t)bh * T * 64;

  // --- staging source addresses (swizzle pre-applied on global side) ---
  int kr = lane >> 3;
  int kcc = ((lane & 7) ^ kr) * 8;
  const f16* kbase = k16 + hb + (size_t)(wid * 32 + kr) * 64 + kcc;
  const f16* vbase0;
  const f16* vbase1;
  const f16* vbase2;
  const f16* vbase3;
  {
    int lr = lane >> 4, lc = lane & 15;
    vbase0 = vT + hb + (size_t)(wid * 16 + 0 + lr) * T + ((lc ^ (0 + lr)) * 8);
    vbase1 = vT + hb + (size_t)(wid * 16 + 4 + lr) * T + ((lc ^ (4 + lr)) * 8);
    vbase2 = vT + hb + (size_t)(wid * 16 + 8 + lr) * T + ((lc ^ (8 + lr)) * 8);
    vbase3 = vT + hb + (size_t)(wid * 16 + 12 + lr) * T + ((lc ^ (12 + lr)) * 8);
  }

  // --- precomputed swizzled LDS read bases (per-lane, kt-loop invariant) ---
  // K read (row i*16+l16, chunk (kk*4+quad)^(l16&7)): base + KOFF + i*1024
  const f16* pK[2];
  pK[0] = lds + l16 * 64 + ((quad ^ (l16 & 7)) * 8);
  pK[1] = lds + l16 * 64 + (((4 + quad) ^ (l16 & 7)) * 8);
  // V read (row i*16+l16, chunk (si*2+(quad>>1))^l16, half quad&1):
  //   base + VOFF + i*2048
  const f16* pV[8];
#pragma unroll
  for (int si = 0; si < 8; ++si)
    pV[si] = lds + l16 * 128 + (((si * 2 + (quad >> 1)) ^ l16) * 8) + (quad & 1) * 4;

#define STAGE(KOFF, VOFF, ktn)                                          \
  do {                                                                  \
    const f16* kp_ = kbase + (size_t)(ktn) * 8192;                      \
    gld16(kp_ + 0 * 512, lds + (KOFF) + (wid * 4 + 0) * 512);           \
    gld16(kp_ + 1 * 512, lds + (KOFF) + (wid * 4 + 1) * 512);           \
    gld16(kp_ + 2 * 512, lds + (KOFF) + (wid * 4 + 2) * 512);           \
    gld16(kp_ + 3 * 512, lds + (KOFF) + (wid * 4 + 3) * 512);           \
    gld16(vbase0 + (ktn) * 128, lds + (VOFF) + (wid * 4 + 0) * 512);    \
    gld16(vbase1 + (ktn) * 128, lds + (VOFF) + (wid * 4 + 1) * 512);    \
    gld16(vbase2 + (ktn) * 128, lds + (VOFF) + (wid * 4 + 2) * 512);    \
    gld16(vbase3 + (ktn) * 128, lds + (VOFF) + (wid * 4 + 3) * 512);    \
  } while (0)

  f16x8 qf[2][2];
#pragma unroll
  for (int g = 0; g < 2; ++g) {
    size_t qrow = hb + (size_t)(qt * 128 + wid * 32 + g * 16 + l16) * 64 + quad * 8;
    qf[g][0] = *(const f16x8*)(q16 + qrow);
    qf[g][1] = *(const f16x8*)(q16 + qrow + 32);
  }
  f16x4 ones4;
  for (int e = 0; e < 4; ++e) ones4[e] = (f16)1.0f;
  const floatx4 Z4 = {0.f, 0.f, 0.f, 0.f};

  float m_i[2] = {-1e30f, -1e30f}, l_i[2] = {0.f, 0.f};
  floatx4 o[2][4] = {};  // O^T per group: dn = i*16 + quad*4 + reg, m = l16

#define COMPUTE(KOFF, VOFF)                                                        \
  do {                                                                             \
    floatx4 sf[2][8];                                                              \
    __builtin_amdgcn_s_setprio(1);                                                 \
    _Pragma("unroll") for (int i = 0; i < 8; ++i) {                                \
      f16x8 kf = *(const f16x8*)(pK[0] + (KOFF) + i * 1024);                       \
      sf[0][i] = __builtin_amdgcn_mfma_f32_16x16x32_f16(kf, qf[0][0], Z4, 0, 0, 0); \
      sf[1][i] = __builtin_amdgcn_mfma_f32_16x16x32_f16(kf, qf[1][0], Z4, 0, 0, 0); \
    }                                                                              \
    _Pragma("unroll") for (int i = 0; i < 8; ++i) {                                \
      f16x8 kf = *(const f16x8*)(pK[1] + (KOFF) + i * 1024);                       \
      sf[0][i] = __builtin_amdgcn_mfma_f32_16x16x32_f16(kf, qf[0][1], sf[0][i], 0, 0, 0); \
      sf[1][i] = __builtin_amdgcn_mfma_f32_16x16x32_f16(kf, qf[1][1], sf[1][i], 0, 0, 0); \
    }                                                                              \
    __builtin_amdgcn_s_setprio(0);                                                 \
    f16x4 pf[2][8];                                                                \
    _Pragma("unroll") for (int g = 0; g < 2; ++g) {                                \
      float t0_ = fmaxf(fmaxf(sf[g][0][0], sf[g][0][1]), fmaxf(sf[g][0][2], sf[g][0][3])); \
      float t1_ = fmaxf(fmaxf(sf[g][1][0], sf[g][1][1]), fmaxf(sf[g][1][2], sf[g][1][3])); \
      float t2_ = fmaxf(fmaxf(sf[g][2][0], sf[g][2][1]), fmaxf(sf[g][2][2], sf[g][2][3])); \
      float t3_ = fmaxf(fmaxf(sf[g][3][0], sf[g][3][1]), fmaxf(sf[g][3][2], sf[g][3][3])); \
      float t4_ = fmaxf(fmaxf(sf[g][4][0], sf[g][4][1]), fmaxf(sf[g][4][2], sf[g][4][3])); \
      float t5_ = fmaxf(fmaxf(sf[g][5][0], sf[g][5][1]), fmaxf(sf[g][5][2], sf[g][5][3])); \
      float t6_ = fmaxf(fmaxf(sf[g][6][0], sf[g][6][1]), fmaxf(sf[g][6][2], sf[g][6][3])); \
      float t7_ = fmaxf(fmaxf(sf[g][7][0], sf[g][7][1]), fmaxf(sf[g][7][2], sf[g][7][3])); \
      float mx = fmaxf(fmaxf(fmaxf(t0_, t1_), fmaxf(t2_, t3_)),                    \
                       fmaxf(fmaxf(t4_, t5_), fmaxf(t6_, t7_)));                   \
      mx = fmaxf(mx, __shfl_xor(mx, 16));                                          \
      mx = fmaxf(mx, __shfl_xor(mx, 32));                                          \
      if (__any(mx > m_i[g] + 8.0f)) {                                             \
        float m_new = fmaxf(m_i[g], mx);                                           \
        float alpha = exp2f(m_i[g] - m_new);                                       \
        m_i[g] = m_new;                                                            \
        _Pragma("unroll") for (int i = 0; i < 4; ++i) o[g][i] *= alpha;            \
        l_i[g] *= alpha;                                                           \
      }                                                                            \
      float mi_ = m_i[g];                                                          \
      _Pragma("unroll") for (int i = 0; i < 8; ++i) {                              \
        union { h16x2 hh; f16 ff[2]; } a2, b2;                                     \
        a2.hh = __builtin_amdgcn_cvt_pkrtz(sf[g][i][0] - mi_, sf[g][i][1] - mi_);  \
        b2.hh = __builtin_amdgcn_cvt_pkrtz(sf[g][i][2] - mi_, sf[g][i][3] - mi_);  \
        f16x4 uu = {a2.ff[0], a2.ff[1], b2.ff[0], b2.ff[1]};                       \
        pf[g][i] = __builtin_elementwise_exp2(uu);                                 \
      }                                                                            \
    }                                                                              \
    __builtin_amdgcn_s_setprio(1);                                                 \
    _Pragma("unroll") for (int g = 0; g < 2; ++g) {                                \
      floatx4 rs0 = __builtin_amdgcn_mfma_f32_16x16x16f16(ones4, pf[g][0], Z4, 0, 0, 0); \
      floatx4 rs1 = __builtin_amdgcn_mfma_f32_16x16x16f16(ones4, pf[g][4], Z4, 0, 0, 0); \
      rs0 = __builtin_amdgcn_mfma_f32_16x16x16f16(ones4, pf[g][1], rs0, 0, 0, 0);  \
      rs1 = __builtin_amdgcn_mfma_f32_16x16x16f16(ones4, pf[g][5], rs1, 0, 0, 0);  \
      rs0 = __builtin_amdgcn_mfma_f32_16x16x16f16(ones4, pf[g][2], rs0, 0, 0, 0);  \
      rs1 = __builtin_amdgcn_mfma_f32_16x16x16f16(ones4, pf[g][6], rs1, 0, 0, 0);  \
      rs0 = __builtin_amdgcn_mfma_f32_16x16x16f16(ones4, pf[g][3], rs0, 0, 0, 0);  \
      rs1 = __builtin_amdgcn_mfma_f32_16x16x16f16(ones4, pf[g][7], rs1, 0, 0, 0);  \
      l_i[g] += rs0[0] + rs1[0];                                                   \
    }                                                                              \
    _Pragma("unroll") for (int i = 0; i < 4; ++i)                                  \
        _Pragma("unroll") for (int si = 0; si < 8; ++si) {                         \
      f16x4 vf = *(const f16x4*)(pV[si] + (VOFF) + i * 2048);                      \
      o[0][i] = __builtin_amdgcn_mfma_f32_16x16x16f16(vf, pf[0][si], o[0][i], 0, 0, 0); \
      o[1][i] = __builtin_amdgcn_mfma_f32_16x16x16f16(vf, pf[1][si], o[1][i], 0, 0, 0); \
    }                                                                              \
    __builtin_amdgcn_s_setprio(0);                                                 \
  } while (0)

  STAGE(0, 16384, 0);
  __syncthreads();  // drains vmcnt: tile 0 staged

#pragma unroll 1
  for (int kt2 = 0; kt2 < 8; ++kt2) {
    STAGE(8192, 24576, 2 * kt2 + 1);  // async prefetch, hides under compute
    COMPUTE(0, 16384);
    __syncthreads();                  // drains vmcnt: tile 2*kt2+1 staged
    if (kt2 < 7) STAGE(0, 16384, 2 * kt2 + 2);
    COMPUTE(8192, 24576);
    if (kt2 < 7) __syncthreads();
  }

  // epilogue: O^T[dn][m] -> y[b, t, h*64+dn]
#pragma unroll
  for (int g = 0; g < 2; ++g) {
    float invl = 1.0f / l_i[g];
    int t = qt * 128 + wid * 32 + g * 16 + l16;
    size_t off = ((size_t)(b * T + t)) * 768 + h * 64;
    for (int i = 0; i < 4; ++i)
      for (int r = 0; r < 4; ++r)
        y[off + i * 16 + quad * 4 + r] = (f16)(o[g][i][r] * invl);
  }
#undef STAGE
#undef COMPUTE
}

extern "C" void kernel_launch(void* const* d_in, const int* in_sizes, int n_in,
                              void* d_out, int out_size, void* d_ws, size_t ws_size,
                              hipStream_t stream) {
  const float* x     = (const float*)d_in[0];  // [4,2048,768] fp32
  const float* Wqkv  = (const float*)d_in[1];  // [768,2304] fp32
  const float* Wproj = (const float*)d_in[2];  // [768,768] fp32
  float* out = (float*)d_out;                  // [4,2048,768] fp32
  char* ws = (char*)d_ws;
  f16* q16    = (f16*)ws;                  // 8192*768*2 = 12,582,912 B each
  f16* k16    = (f16*)(ws + 12582912);
  f16* vT16   = (f16*)(ws + 25165824);
  f16* y16    = (f16*)(ws + 37748736);
  f16* WqkvT  = (f16*)(ws + 50331648);     // 2304*768*2 = 3,538,944 B
  f16* WprojT = (f16*)(ws + 53870592);     //  768*768*2 = 1,179,648 B
  // x16 lives in the y16 slot: consumed by gemm1 before flash_attn writes y16
  f16* x16 = y16;

  cvt_f32_f16<<<3072, 256, 0, stream>>>(x, x16);
  transpose_f32_f16_tiled<<<dim3(12, 36), 256, 0, stream>>>(Wqkv, WqkvT, 768, 2304);
  transpose_f32_f16_tiled<<<dim3(12, 12), 256, 0, stream>>>(Wproj, WprojT, 768, 768);
  gemm1_qkv<<<dim3(64, 18), 256, 0, stream>>>(x16, WqkvT, q16, k16, vT16);
  flash_attn<<<768, 256, 0, stream>>>(q16, k16, vT16, y16);
  gemm_bt_f16<<<dim3(64, 6), 256, 0, stream>>>(y16, WprojT, out, 8192, 768, 768);
}

// Round 4
// 254.138 us; speedup vs baseline: 1.1484x; 1.1484x over previous
//
#include <hip/hip_runtime.h>

typedef _Float16 f16;
typedef f16 f16x4 __attribute__((ext_vector_type(4)));
typedef f16 f16x8 __attribute__((ext_vector_type(8)));
typedef __fp16 h16x2 __attribute__((ext_vector_type(2)));
typedef float floatx4 __attribute__((ext_vector_type(4)));

#define LDT 72  // 64+8 pad f16 stride for GEMM tiles: fragment reads are 2-way (free)
#define LDE 136 // epilogue V-transpose tile stride (16B-aligned rows for uint4)
#define QSCALE 11.5415603271117f  // 8 * log2(e): score computed in log2 domain

// direct global->LDS DMA, 16B per lane. LDS dest is WAVE-UNIFORM base;
// HW scatters lane i at base + i*16B. Global src is per-lane.
__device__ __forceinline__ void gld16(const void* g, void* l) {
  __builtin_amdgcn_global_load_lds((const __attribute__((address_space(1))) unsigned int*)g,
                                   (__attribute__((address_space(3))) unsigned int*)l,
                                   16, 0, 0);
}

// W [K][N] fp32 -> Wt [N][K] fp16, 64x64 tiles via LDS: coalesced both sides
__global__ __launch_bounds__(256) void transpose_f32_f16_tiled(const float* __restrict__ in,
                                                               f16* __restrict__ out,
                                                               int K, int N) {
  __shared__ f16 tile[64][LDT];
  int k0 = blockIdx.x * 64, n0 = blockIdx.y * 64;
  int tid = threadIdx.x;
  int r = tid >> 4, c4 = (tid & 15) * 4;
  for (int p = 0; p < 4; ++p) {
    int rr = r + p * 16;
    float4 v = *(const float4*)(in + (size_t)(k0 + rr) * N + n0 + c4);
    tile[c4 + 0][rr] = (f16)v.x;
    tile[c4 + 1][rr] = (f16)v.y;
    tile[c4 + 2][rr] = (f16)v.z;
    tile[c4 + 3][rr] = (f16)v.w;
  }
  __syncthreads();
  int rn = tid >> 3, ck = (tid & 7) * 8;
  for (int p = 0; p < 2; ++p) {
    int rr = rn + p * 32;
    *(uint4*)(out + (size_t)(n0 + rr) * K + k0 + ck) = *(const uint4*)(&tile[rr][ck]);
  }
}

// qkv = x @ WqkvT^T (x fp32 converted during staging, fp32 acc). Epilogue scatters:
//   cols [0,768):     q16 [bh][t][64], PRE-SCALED by 8*log2(e)
//   cols [768,1536):  k16 [bh][t][64]
//   cols [1536,2304): vT  [bh][64][2048] via LDS transpose -> coalesced 256B rows
// R0-proven variant (reg staging, LDT=72): measured faster than gld16 form here
// (K=768 short loop + heavy epilogue; R0 242.6 vs R1 250.8 total).
__global__ __launch_bounds__(256) void gemm1_qkv(const float* __restrict__ A,
                                                 const f16* __restrict__ Bt,
                                                 f16* __restrict__ q16, f16* __restrict__ k16,
                                                 f16* __restrict__ vt) {
  __shared__ f16 smem[2 * 128 * LDT];  // As | Bs; reused as V-transpose tile in epilogue
  f16* As = smem;
  f16* Bs = smem + 128 * LDT;
  int tid = threadIdx.x;
  int lane = tid & 63, wid = tid >> 6;
  int quad = lane >> 4, l16 = lane & 15;
  int wy = wid >> 1, wx = wid & 1;
  int m0 = blockIdx.x * 128, n0 = blockIdx.y * 128;
  int srow = tid >> 3, scol = (tid & 7) * 8;
  floatx4 acc[4][4] = {};
  for (int k0 = 0; k0 < 768; k0 += 64) {
    for (int p = 0; p < 4; ++p) {
      int r = srow + p * 32;
      const float* src = A + (size_t)(m0 + r) * 768 + k0 + scol;
      float4 v0 = *(const float4*)(src);
      float4 v1 = *(const float4*)(src + 4);
      f16x8 hv = {(f16)v0.x, (f16)v0.y, (f16)v0.z, (f16)v0.w,
                  (f16)v1.x, (f16)v1.y, (f16)v1.z, (f16)v1.w};
      *(f16x8*)(As + r * LDT + scol) = hv;
      *(uint4*)(Bs + r * LDT + scol) = *(const uint4*)(Bt + (size_t)(n0 + r) * 768 + k0 + scol);
    }
    __syncthreads();
    for (int kk = 0; kk < 64; kk += 32) {
      f16x8 af[4], bfr[4];
      for (int i = 0; i < 4; ++i)
        af[i] = *(const f16x8*)(As + (wy * 64 + i * 16 + l16) * LDT + kk + quad * 8);
      for (int j = 0; j < 4; ++j)
        bfr[j] = *(const f16x8*)(Bs + (wx * 64 + j * 16 + l16) * LDT + kk + quad * 8);
      for (int i = 0; i < 4; ++i)
        for (int j = 0; j < 4; ++j)
          acc[i][j] = __builtin_amdgcn_mfma_f32_16x16x32_f16(af[i], bfr[j], acc[i][j], 0, 0, 0);
    }
    __syncthreads();  // also guarantees LDS reads done before epilogue reuse
  }
  int b = m0 >> 11, t0 = m0 & 2047;
  if (n0 < 1536) {
    for (int i = 0; i < 4; ++i)
      for (int j = 0; j < 4; ++j)
        for (int r = 0; r < 4; ++r) {
          int t = t0 + wy * 64 + i * 16 + quad * 4 + r;
          int col = n0 + wx * 64 + j * 16 + l16;
          float a = acc[i][j][r];
          if (col < 768) {
            int h = col >> 6, d = col & 63;
            q16[((size_t)(b * 12 + h)) * 131072 + (size_t)t * 64 + d] = (f16)(a * QSCALE);
          } else {
            int c = col - 768;
            int h = c >> 6, d = c & 63;
            k16[((size_t)(b * 12 + h)) * 131072 + (size_t)t * 64 + d] = (f16)a;
          }
        }
  } else {
    // V block: acc -> LDS [col][row], then coalesced row-major vt writes
    f16* Vtile = smem;  // 128*LDE = 34816 B <= 36864 B
    int h0 = (n0 - 1536) >> 6;
    for (int i = 0; i < 4; ++i)
      for (int j = 0; j < 4; ++j) {
        int cl = wx * 64 + j * 16 + l16;
        int rl = wy * 64 + i * 16 + quad * 4;
        for (int r = 0; r < 4; ++r)
          Vtile[cl * LDE + rl + r] = (f16)acc[i][j][r];
      }
    __syncthreads();
    int u = tid & 15;  // 16 lanes cover one row: 16 x 16B = 256B contiguous
    for (int p = 0; p < 8; ++p) {
      int c = (tid >> 4) + p * 16;
      *(uint4*)(vt + ((size_t)(b * 12 + h0 + (c >> 6))) * 131072 +
                (size_t)(c & 63) * 2048 + t0 + u * 8) =
          *(const uint4*)(Vtile + c * LDE + u * 8);
    }
  }
}

// C[M,N](fp32) = A[M,K](f16) * Bt[N,K]^T(f16) — R0-proven reg-staging variant
__global__ __launch_bounds__(256) void gemm_bt_f16(const f16* __restrict__ A,
                                                   const f16* __restrict__ Bt,
                                                   float* __restrict__ C,
                                                   int M, int N, int K) {
  __shared__ f16 As[128 * LDT];
  __shared__ f16 Bs[128 * LDT];
  int tid = threadIdx.x;
  int lane = tid & 63, wid = tid >> 6;
  int quad = lane >> 4, l16 = lane & 15;
  int wy = wid >> 1, wx = wid & 1;
  int m0 = blockIdx.x * 128, n0 = blockIdx.y * 128;
  int srow = tid >> 3, scol = (tid & 7) * 8;
  floatx4 acc[4][4] = {};
  for (int k0 = 0; k0 < K; k0 += 64) {
    for (int p = 0; p < 4; ++p) {
      int r = srow + p * 32;
      *(uint4*)(As + r * LDT + scol) = *(const uint4*)(A + (size_t)(m0 + r) * K + k0 + scol);
      *(uint4*)(Bs + r * LDT + scol) = *(const uint4*)(Bt + (size_t)(n0 + r) * K + k0 + scol);
    }
    __syncthreads();
    for (int kk = 0; kk < 64; kk += 32) {
      f16x8 af[4], bfr[4];
      for (int i = 0; i < 4; ++i)
        af[i] = *(const f16x8*)(As + (wy * 64 + i * 16 + l16) * LDT + kk + quad * 8);
      for (int j = 0; j < 4; ++j)
        bfr[j] = *(const f16x8*)(Bs + (wx * 64 + j * 16 + l16) * LDT + kk + quad * 8);
      for (int i = 0; i < 4; ++i)
        for (int j = 0; j < 4; ++j)
          acc[i][j] = __builtin_amdgcn_mfma_f32_16x16x32_f16(af[i], bfr[j], acc[i][j], 0, 0, 0);
    }
    __syncthreads();
  }
  for (int i = 0; i < 4; ++i) {
    int row = m0 + wy * 64 + i * 16 + quad * 4;
    for (int j = 0; j < 4; ++j) {
      int col = n0 + wx * 64 + j * 16 + l16;
      for (int r = 0; r < 4; ++r)
        C[(size_t)(row + r) * N + col] = acc[i][j][r];
    }
  }
}

// Flash attention v11: v9 structure (4 waves x 32 q-rows, dbuf gld_lds staging,
// proven 101 us) + the VALU diet WITHOUT the v10 poison:
//  - precomputed INTEGER LDS read offsets (reads stay directly on the __shared__
//    array -> ds_read inference trivial; per-read VALU ~1 add, const part folds
//    into the 16-bit ds offset immediate)
//  - const-zero MFMA accumulator init (no per-kt v_mov zero blocks)
//  - balanced max tree (depth 5 vs 31 serial)
//  - split rowsum into 2 independent 4-MFMA chains
//  - NO branches (always rescale: v10's defer-max branches split the block and
//    defeated compiler interleave -> 43% stall), NO setprio (same reason).
__global__ __launch_bounds__(256, 1) void flash_attn(const f16* __restrict__ q16,
                                                     const f16* __restrict__ k16,
                                                     const f16* __restrict__ vT,
                                                     f16* __restrict__ y) {
  // f16-unit layout: KsA@0 KsB@8192 VtA@16384 VtB@24576 (64 KB total).
  // Max read byte offset: (24576 + 3*2048 + pad)*2 < 65536 — fits ds imm.
  __shared__ f16 lds[32768];
  const int T = 2048;
  // XCD-locality remap: all 16 q-tiles of a head land on one XCD's L2
  int xcd = blockIdx.x & 7, yb = blockIdx.x >> 3;  // yb in [0,96)
  int bh = xcd * 6 + (yb >> 4);
  int qt = yb & 15;
  int b = bh / 12, h = bh - b * 12;
  int tid = threadIdx.x;
  int lane = tid & 63, wid = tid >> 6;             // wid in [0,4)
  int quad = lane >> 4, l16 = lane & 15;
  size_t hb = (size_t)bh * T * 64;

  // --- staging source addresses (swizzle pre-applied on global side) ---
  int kr = lane >> 3;
  int kcc = ((lane & 7) ^ kr) * 8;
  const f16* kbase = k16 + hb + (size_t)(wid * 32 + kr) * 64 + kcc;
  const f16* vbase0;
  const f16* vbase1;
  const f16* vbase2;
  const f16* vbase3;
  {
    int lr = lane >> 4, lc = lane & 15;
    vbase0 = vT + hb + (size_t)(wid * 16 + 0 + lr) * T + ((lc ^ (0 + lr)) * 8);
    vbase1 = vT + hb + (size_t)(wid * 16 + 4 + lr) * T + ((lc ^ (4 + lr)) * 8);
    vbase2 = vT + hb + (size_t)(wid * 16 + 8 + lr) * T + ((lc ^ (8 + lr)) * 8);
    vbase3 = vT + hb + (size_t)(wid * 16 + 12 + lr) * T + ((lc ^ (12 + lr)) * 8);
  }

  // --- precomputed INTEGER LDS read offsets (f16 units, kt-loop invariant) ---
  // K read (row i*16+l16, chunk (kk*4+quad)^(l16&7)): lds[kb{kk} + KOFF + i*1024]
  int kb0 = l16 * 64 + ((quad ^ (l16 & 7)) * 8);
  int kb1 = l16 * 64 + (((4 + quad) ^ (l16 & 7)) * 8);
  // V read (row i*16+l16, chunk (si*2+(quad>>1))^l16, half quad&1):
  //   lds[vb[si] + VOFF + i*2048]
  int vb[8];
#pragma unroll
  for (int si = 0; si < 8; ++si)
    vb[si] = l16 * 128 + (((si * 2 + (quad >> 1)) ^ l16) * 8) + (quad & 1) * 4;

#define STAGE(KOFF, VOFF, ktn)                                          \
  do {                                                                  \
    const f16* kp_ = kbase + (size_t)(ktn) * 8192;                      \
    gld16(kp_ + 0 * 512, lds + (KOFF) + (wid * 4 + 0) * 512);           \
    gld16(kp_ + 1 * 512, lds + (KOFF) + (wid * 4 + 1) * 512);           \
    gld16(kp_ + 2 * 512, lds + (KOFF) + (wid * 4 + 2) * 512);           \
    gld16(kp_ + 3 * 512, lds + (KOFF) + (wid * 4 + 3) * 512);           \
    gld16(vbase0 + (ktn) * 128, lds + (VOFF) + (wid * 4 + 0) * 512);    \
    gld16(vbase1 + (ktn) * 128, lds + (VOFF) + (wid * 4 + 1) * 512);    \
    gld16(vbase2 + (ktn) * 128, lds + (VOFF) + (wid * 4 + 2) * 512);    \
    gld16(vbase3 + (ktn) * 128, lds + (VOFF) + (wid * 4 + 3) * 512);    \
  } while (0)

  // Q fragments: 32 q-rows per wave (2 groups of 16), B-operand m = l16
  f16x8 qf[2][2];
#pragma unroll
  for (int g = 0; g < 2; ++g) {
    size_t qrow = hb + (size_t)(qt * 128 + wid * 32 + g * 16 + l16) * 64 + quad * 8;
    qf[g][0] = *(const f16x8*)(q16 + qrow);
    qf[g][1] = *(const f16x8*)(q16 + qrow + 32);
  }
  f16x4 ones4;
  for (int e = 0; e < 4; ++e) ones4[e] = (f16)1.0f;
  const floatx4 Z4 = {0.f, 0.f, 0.f, 0.f};

  float m_i[2] = {-1e30f, -1e30f}, l_i[2] = {0.f, 0.f};
  floatx4 o[2][4] = {};  // O^T per group: dn = i*16 + quad*4 + reg, m = l16

#define COMPUTE(KOFF, VOFF)                                                        \
  do {                                                                             \
    floatx4 sf[2][8];                                                              \
    _Pragma("unroll") for (int i = 0; i < 8; ++i) {                                \
      f16x8 kf = *(const f16x8*)(&lds[kb0 + (KOFF) + i * 1024]);                   \
      sf[0][i] = __builtin_amdgcn_mfma_f32_16x16x32_f16(kf, qf[0][0], Z4, 0, 0, 0); \
      sf[1][i] = __builtin_amdgcn_mfma_f32_16x16x32_f16(kf, qf[1][0], Z4, 0, 0, 0); \
    }                                                                              \
    _Pragma("unroll") for (int i = 0; i < 8; ++i) {                                \
      f16x8 kf = *(const f16x8*)(&lds[kb1 + (KOFF) + i * 1024]);                   \
      sf[0][i] = __builtin_amdgcn_mfma_f32_16x16x32_f16(kf, qf[0][1], sf[0][i], 0, 0, 0); \
      sf[1][i] = __builtin_amdgcn_mfma_f32_16x16x32_f16(kf, qf[1][1], sf[1][i], 0, 0, 0); \
    }                                                                              \
    f16x4 pf[2][8];                                                                \
    _Pragma("unroll") for (int g = 0; g < 2; ++g) {                                \
      float t0_ = fmaxf(fmaxf(sf[g][0][0], sf[g][0][1]), fmaxf(sf[g][0][2], sf[g][0][3])); \
      float t1_ = fmaxf(fmaxf(sf[g][1][0], sf[g][1][1]), fmaxf(sf[g][1][2], sf[g][1][3])); \
      float t2_ = fmaxf(fmaxf(sf[g][2][0], sf[g][2][1]), fmaxf(sf[g][2][2], sf[g][2][3])); \
      float t3_ = fmaxf(fmaxf(sf[g][3][0], sf[g][3][1]), fmaxf(sf[g][3][2], sf[g][3][3])); \
      float t4_ = fmaxf(fmaxf(sf[g][4][0], sf[g][4][1]), fmaxf(sf[g][4][2], sf[g][4][3])); \
      float t5_ = fmaxf(fmaxf(sf[g][5][0], sf[g][5][1]), fmaxf(sf[g][5][2], sf[g][5][3])); \
      float t6_ = fmaxf(fmaxf(sf[g][6][0], sf[g][6][1]), fmaxf(sf[g][6][2], sf[g][6][3])); \
      float t7_ = fmaxf(fmaxf(sf[g][7][0], sf[g][7][1]), fmaxf(sf[g][7][2], sf[g][7][3])); \
      float mx = fmaxf(fmaxf(fmaxf(t0_, t1_), fmaxf(t2_, t3_)),                    \
                       fmaxf(fmaxf(t4_, t5_), fmaxf(t6_, t7_)));                   \
      mx = fmaxf(mx, __shfl_xor(mx, 16));                                          \
      mx = fmaxf(mx, __shfl_xor(mx, 32));                                          \
      float m_new = fmaxf(m_i[g], mx);                                             \
      float alpha = exp2f(m_i[g] - m_new);                                         \
      m_i[g] = m_new;                                                              \
      _Pragma("unroll") for (int i = 0; i < 4; ++i) o[g][i] *= alpha;              \
      l_i[g] *= alpha;                                                             \
      _Pragma("unroll") for (int i = 0; i < 8; ++i) {                              \
        union { h16x2 hh; f16 ff[2]; } a2, b2;                                     \
        a2.hh = __builtin_amdgcn_cvt_pkrtz(sf[g][i][0] - m_new, sf[g][i][1] - m_new); \
        b2.hh = __builtin_amdgcn_cvt_pkrtz(sf[g][i][2] - m_new, sf[g][i][3] - m_new); \
        f16x4 uu = {a2.ff[0], a2.ff[1], b2.ff[0], b2.ff[1]};                       \
        pf[g][i] = __builtin_elementwise_exp2(uu);                                 \
      }                                                                            \
    }                                                                              \
    _Pragma("unroll") for (int g = 0; g < 2; ++g) {                                \
      floatx4 rs0 = __builtin_amdgcn_mfma_f32_16x16x16f16(ones4, pf[g][0], Z4, 0, 0, 0); \
      floatx4 rs1 = __builtin_amdgcn_mfma_f32_16x16x16f16(ones4, pf[g][4], Z4, 0, 0, 0); \
      rs0 = __builtin_amdgcn_mfma_f32_16x16x16f16(ones4, pf[g][1], rs0, 0, 0, 0);  \
      rs1 = __builtin_amdgcn_mfma_f32_16x16x16f16(ones4, pf[g][5], rs1, 0, 0, 0);  \
      rs0 = __builtin_amdgcn_mfma_f32_16x16x16f16(ones4, pf[g][2], rs0, 0, 0, 0);  \
      rs1 = __builtin_amdgcn_mfma_f32_16x16x16f16(ones4, pf[g][6], rs1, 0, 0, 0);  \
      rs0 = __builtin_amdgcn_mfma_f32_16x16x16f16(ones4, pf[g][3], rs0, 0, 0, 0);  \
      rs1 = __builtin_amdgcn_mfma_f32_16x16x16f16(ones4, pf[g][7], rs1, 0, 0, 0);  \
      l_i[g] += rs0[0] + rs1[0];                                                   \
    }                                                                              \
    _Pragma("unroll") for (int i = 0; i < 4; ++i)                                  \
        _Pragma("unroll") for (int si = 0; si < 8; ++si) {                         \
      f16x4 vf = *(const f16x4*)(&lds[vb[si] + (VOFF) + i * 2048]);                \
      o[0][i] = __builtin_amdgcn_mfma_f32_16x16x16f16(vf, pf[0][si], o[0][i], 0, 0, 0); \
      o[1][i] = __builtin_amdgcn_mfma_f32_16x16x16f16(vf, pf[1][si], o[1][i], 0, 0, 0); \
    }                                                                              \
  } while (0)

  STAGE(0, 16384, 0);
  __syncthreads();  // drains vmcnt: tile 0 staged

#pragma unroll 1
  for (int kt2 = 0; kt2 < 8; ++kt2) {
    STAGE(8192, 24576, 2 * kt2 + 1);  // async prefetch, hides under compute
    COMPUTE(0, 16384);
    __syncthreads();                  // drains vmcnt: tile 2*kt2+1 staged
    if (kt2 < 7) STAGE(0, 16384, 2 * kt2 + 2);
    COMPUTE(8192, 24576);
    if (kt2 < 7) __syncthreads();
  }

  // epilogue: O^T[dn][m] -> y[b, t, h*64+dn]
#pragma unroll
  for (int g = 0; g < 2; ++g) {
    float invl = 1.0f / l_i[g];
    int t = qt * 128 + wid * 32 + g * 16 + l16;
    size_t off = ((size_t)(b * T + t)) * 768 + h * 64;
    for (int i = 0; i < 4; ++i)
      for (int r = 0; r < 4; ++r)
        y[off + i * 16 + quad * 4 + r] = (f16)(o[g][i][r] * invl);
  }
#undef STAGE
#undef COMPUTE
}

extern "C" void kernel_launch(void* const* d_in, const int* in_sizes, int n_in,
                              void* d_out, int out_size, void* d_ws, size_t ws_size,
                              hipStream_t stream) {
  const float* x     = (const float*)d_in[0];  // [4,2048,768] fp32
  const float* Wqkv  = (const float*)d_in[1];  // [768,2304] fp32
  const float* Wproj = (const float*)d_in[2];  // [768,768] fp32
  float* out = (float*)d_out;                  // [4,2048,768] fp32
  char* ws = (char*)d_ws;
  f16* q16    = (f16*)ws;                  // 8192*768*2 = 12,582,912 B each
  f16* k16    = (f16*)(ws + 12582912);
  f16* vT16   = (f16*)(ws + 25165824);
  f16* y16    = (f16*)(ws + 37748736);
  f16* WqkvT  = (f16*)(ws + 50331648);     // 2304*768*2 = 3,538,944 B
  f16* WprojT = (f16*)(ws + 53870592);     //  768*768*2 = 1,179,648 B
                                           // total 55,050,240 B

  transpose_f32_f16_tiled<<<dim3(12, 36), 256, 0, stream>>>(Wqkv, WqkvT, 768, 2304);
  transpose_f32_f16_tiled<<<dim3(12, 12), 256, 0, stream>>>(Wproj, WprojT, 768, 768);
  gemm1_qkv<<<dim3(64, 18), 256, 0, stream>>>(x, WqkvT, q16, k16, vT16);
  flash_attn<<<768, 256, 0, stream>>>(q16, k16, vT16, y16);
  gemm_bt_f16<<<dim3(64, 6), 256, 0, stream>>>(y16, WprojT, out, 8192, 768, 768);
}